// Round 9
// baseline (840.959 us; speedup 1.0000x reference)
//
#include <hip/hip_runtime.h>
#include <hip/hip_bf16.h>

// Fused Comm_OUT pipeline, batch-row-parallel (GRU recurrence is per-row).
// Round-9: identical to round-8 wave-specialized pipeline EXCEPT
// __launch_bounds__(1024, 2): empirically the compiler allocates
// VGPR ~= 256/min-waves-arg ((512,2)->128, (512,4)->64, (1024,4)->64),
// and r8's (1024,4) forced 64 VGPR -> gi/gh spilled to scratch (WRITE_SIZE
// 381 MB, FETCH +0.6 GB, dur 750us). (1024,2) targets 128 VGPR; 16-wave
// block launchability independently caps at 128, so residency unchanged
// (4 waves/SIMD, 1 block/CU). This is the clean test of tail-overlap.
// waves 0..7 = GRU (gh MFMA + gates), waves 8..15 = tail (Wc at t-1,
// Wmu->out at t-2), double-buffered yb/zb, 2 barriers/iteration.
// Runtime dtype detection (inputs fp32 or bf16) via g_flag.

typedef __attribute__((ext_vector_type(8))) short bf16x8;   // 8 x bf16 (4 VGPRs)
typedef __attribute__((ext_vector_type(4))) float f32x4;    // MFMA accumulator

#define MFMA16(a, b, c) __builtin_amdgcn_mfma_f32_16x16x32_bf16((a), (b), (c), 0, 0, 0)

constexpr int F   = 640;
constexpr int H   = 256;
constexpr int LSTEPS = 20;
constexpr int CO  = 32;
constexpr int LDP = 264;   // padded bf16 row stride (16B-aligned rows)

// packed-weight element offsets inside g_wpk
constexpr size_t WHH_E  = 0;                    // 8cg*3g*8kk*2j*64lane*8 = 196608
constexpr size_t WIH_E  = 196608;               // 196608
constexpr size_t WC_E   = 393216;               // 8cg*8kk*2j*64*8       = 65536
constexpr size_t WMU_E  = 458752;               // 2nt*8kk*64*8          = 8192
constexpr size_t WLIN_E = 466944;               // 8cg*20kk*2j*64*8      = 163840
constexpr size_t PK_ELEMS = 630784;

__device__ __align__(16) unsigned short g_wpk[PK_ELEMS];
__device__ int g_flag;     // 1 = inputs are fp32

__device__ __forceinline__ float bf2f(__hip_bfloat16 x) { return __bfloat162float(x); }
__device__ __forceinline__ unsigned short f2bs(float f) {
    __hip_bfloat16 h = __float2bfloat16(f);
    return *reinterpret_cast<unsigned short*>(&h);
}
__device__ __forceinline__ bf16x8 lds8(const unsigned short* p) {
    return *reinterpret_cast<const bf16x8*>(p);
}
__device__ __forceinline__ bf16x8 pk8(size_t eoff) {
    return *reinterpret_cast<const bf16x8*>(g_wpk + eoff);
}
__device__ __forceinline__ float sigm(float x) {
    return 1.0f / (1.0f + __expf(-x));
}

template<bool F32>
__device__ __forceinline__ bf16x8 g8(const void* base, size_t off) {
    if constexpr (!F32) {
        return *reinterpret_cast<const bf16x8*>((const __hip_bfloat16*)base + off);
    } else {
        const float* f = (const float*)base + off;
        float4 lo = *reinterpret_cast<const float4*>(f);
        float4 hi = *reinterpret_cast<const float4*>(f + 4);
        bf16x8 r;
        r[0] = (short)f2bs(lo.x); r[1] = (short)f2bs(lo.y);
        r[2] = (short)f2bs(lo.z); r[3] = (short)f2bs(lo.w);
        r[4] = (short)f2bs(hi.x); r[5] = (short)f2bs(hi.y);
        r[6] = (short)f2bs(hi.z); r[7] = (short)f2bs(hi.w);
        return r;
    }
}

template<bool F32>
__device__ __forceinline__ float ld1(const void* base, int i) {
    if constexpr (!F32) return bf2f(((const __hip_bfloat16*)base)[i]);
    else                return ((const float*)base)[i];
}

// ---------------- dtype detect: v1 (uniform[0.5,1.5]) ----------------
__global__ void detect_dtype(const void* v1) {
    const unsigned short* u = (const unsigned short*)v1;
    int f32 = 0;
    for (int i = 0; i < 8; ++i) {
        unsigned short s = u[i];
        __hip_bfloat16 h = *reinterpret_cast<__hip_bfloat16*>(&s);
        float v = __bfloat162float(h);
        if (!(v >= 0.25f && v <= 2.0f)) f32 = 1;
    }
    g_flag = f32;
}

// ---------------- weight pre-pack (fp32|bf16 -> bf16 fragment streams) ----------------
__device__ __forceinline__ unsigned short cvt1(const void* p, size_t i, bool f32) {
    if (f32) return f2bs(((const float*)p)[i]);
    return ((const unsigned short*)p)[i];
}

__global__ void prepack(const void* Wlin, const void* Wih, const void* Whh,
                        const void* Wc, const void* Wmu) {
    const bool f32 = (g_flag != 0);
    const int gid = blockIdx.x * 256 + threadIdx.x;
    const void* src;
    size_t dbase;
    int row, col0, ncols;
    if (gid < 24576) {                       // Whh [768,256]
        int idx = gid;
        int lane = idx & 63, j = (idx >> 6) & 1, kk = (idx >> 7) & 7;
        int t2 = idx >> 10, g = t2 % 3, w = t2 / 3;
        row = g * 256 + w * 32 + j * 16 + (lane & 15);
        col0 = kk * 32 + (lane >> 4) * 8;
        ncols = 256; src = Whh; dbase = WHH_E + (size_t)idx * 8;
    } else if (gid < 49152) {                // Wih [768,256]
        int idx = gid - 24576;
        int lane = idx & 63, j = (idx >> 6) & 1, kk = (idx >> 7) & 7;
        int t2 = idx >> 10, g = t2 % 3, w = t2 / 3;
        row = g * 256 + w * 32 + j * 16 + (lane & 15);
        col0 = kk * 32 + (lane >> 4) * 8;
        ncols = 256; src = Wih; dbase = WIH_E + (size_t)idx * 8;
    } else if (gid < 57344) {                // Wc [256,256]
        int idx = gid - 49152;
        int lane = idx & 63, j = (idx >> 6) & 1, kk = (idx >> 7) & 7, w = idx >> 10;
        row = w * 32 + j * 16 + (lane & 15);
        col0 = kk * 32 + (lane >> 4) * 8;
        ncols = 256; src = Wc; dbase = WC_E + (size_t)idx * 8;
    } else if (gid < 58368) {                // Wmu [32,256]
        int idx = gid - 57344;
        int lane = idx & 63, kk = (idx >> 6) & 7, w = idx >> 9;
        row = w * 16 + (lane & 15);
        col0 = kk * 32 + (lane >> 4) * 8;
        ncols = 256; src = Wmu; dbase = WMU_E + (size_t)idx * 8;
    } else if (gid < 78848) {                // Wlin [256,640]
        int idx = gid - 58368;
        int lane = idx & 63, j = (idx >> 6) & 1;
        int t1 = idx >> 7, kk = t1 % 20, w = t1 / 20;
        row = w * 32 + j * 16 + (lane & 15);
        col0 = kk * 32 + (lane >> 4) * 8;
        ncols = 640; src = Wlin; dbase = WLIN_E + (size_t)idx * 8;
    } else {
        return;
    }
    const size_t s0 = (size_t)row * ncols + col0;
    #pragma unroll
    for (int i = 0; i < 8; ++i) g_wpk[dbase + i] = cvt1(src, s0 + i, f32);
}

// ---------------- FAST PATH: 16 waves = 8 GRU + 8 tail, pipelined ----------------
template<bool F32>
__device__ __forceinline__ void fast_pipe(
    const void* hw, const void* blin,
    const void* g1, const void* be1, const void* m1, const void* v1, const void* a1,
    const void* bih, const void* bhh,
    const void* g2, const void* be2, const void* m2, const void* v2, const void* a2,
    const void* bc,
    const void* g3, const void* be3, const void* m3, const void* v3, const void* a3,
    const void* bmu,
    void* out,
    unsigned short* hb, unsigned short* yb0, unsigned short* yb1,
    unsigned short* zb0, unsigned short* zb1)
{
    const int tid  = threadIdx.x;
    const int w    = tid >> 6;        // 0..15
    const bool isG = (w < 8);         // GRU waves vs tail waves
    const int cg   = w & 7;           // column group (32 cols) within role
    const int lane = tid & 63;
    const int m16  = lane & 15;
    const int q    = lane >> 4;
    const int row0 = blockIdx.x * 32;
    const int c0 = cg * 32 + m16;
    const int c1 = c0 + 16;
    const int cc2[2] = { c0, c1 };
    const size_t lane8 = (size_t)lane * 8;
    unsigned short* ybs[2] = { yb0, yb1 };
    unsigned short* zbs[2] = { zb0, zb1 };

    // persistent per-step params (folded); both roles load their own set
    float s2v[2], t2v[2], s3v[2], t3f[2], bhhn[2];
    #pragma unroll
    for (int j = 0; j < 2; ++j) {
        const int cc = cc2[j];
        float s;
        s = ld1<F32>(g2, cc) * rsqrtf(ld1<F32>(v2, cc) + 1e-5f);
        s2v[j] = s; t2v[j] = ld1<F32>(be2, cc) - ld1<F32>(m2, cc) * s;
        s = ld1<F32>(g3, cc) * rsqrtf(ld1<F32>(v3, cc) + 1e-5f);
        s3v[j] = s;
        t3f[j] = (ld1<F32>(bc, cc) - ld1<F32>(m3, cc)) * s + ld1<F32>(be3, cc);
        bhhn[j] = ld1<F32>(bhh, 2 * H + cc);
    }
    const float a2v = ld1<F32>(a2, 0), a3v = ld1<F32>(a3, 0);

    // ---- Phase 1 (GRU waves): x = prelu(bn1(rows @ Wlin^T + blin)) -> zb0 ----
    if (isG) {
        f32x4 xacc[2][2] = {};   // [mt][j]
        #pragma unroll 5
        for (int kk = 0; kk < F / 32; ++kk) {
            bf16x8 a0 = g8<F32>(hw, (size_t)(row0 + m16) * F + kk * 32 + q * 8);
            bf16x8 a1 = g8<F32>(hw, (size_t)(row0 + 16 + m16) * F + kk * 32 + q * 8);
            bf16x8 b0 = pk8(WLIN_E + (size_t)((cg * 20 + kk) * 2 + 0) * 512 + lane8);
            bf16x8 b1 = pk8(WLIN_E + (size_t)((cg * 20 + kk) * 2 + 1) * 512 + lane8);
            xacc[0][0] = MFMA16(a0, b0, xacc[0][0]);
            xacc[1][0] = MFMA16(a1, b0, xacc[1][0]);
            xacc[0][1] = MFMA16(a0, b1, xacc[0][1]);
            xacc[1][1] = MFMA16(a1, b1, xacc[1][1]);
        }
        #pragma unroll
        for (int j = 0; j < 2; ++j) {
            const int cc = cc2[j];
            float s = ld1<F32>(g1, cc) * rsqrtf(ld1<F32>(v1, cc) + 1e-5f);
            float t = ld1<F32>(be1, cc) - ld1<F32>(m1, cc) * s;
            float bl = ld1<F32>(blin, cc);
            float av = ld1<F32>(a1, 0);
            #pragma unroll
            for (int mt = 0; mt < 2; ++mt)
                #pragma unroll
                for (int r = 0; r < 4; ++r) {
                    float vv = (xacc[mt][j][r] + bl) * s + t;
                    vv = (vv >= 0.0f) ? vv : av * vv;
                    zb0[(mt * 16 + q * 4 + r) * LDP + cc] = f2bs(vv);
                }
        }
    }
    __syncthreads();   // x visible in zb0

    // ---- Phase 2 (GRU waves): gi = x @ Wih^T + (bih + bhh[r,z]) ----
    f32x4 gi[2][3][2] = {};   // [mt][g][j]
    if (isG) {
        const unsigned short* xa0 = zb0 + m16 * LDP + q * 8;
        const unsigned short* xa1 = xa0 + 16 * LDP;
        #pragma unroll
        for (int g = 0; g < 3; ++g)
            #pragma unroll
            for (int kk = 0; kk < 8; ++kk) {
                bf16x8 a0 = lds8(xa0 + kk * 32);
                bf16x8 a1 = lds8(xa1 + kk * 32);
                bf16x8 b0 = pk8(WIH_E + (size_t)(((cg * 3 + g) * 8 + kk) * 2 + 0) * 512 + lane8);
                bf16x8 b1 = pk8(WIH_E + (size_t)(((cg * 3 + g) * 8 + kk) * 2 + 1) * 512 + lane8);
                gi[0][g][0] = MFMA16(a0, b0, gi[0][g][0]);
                gi[1][g][0] = MFMA16(a1, b0, gi[1][g][0]);
                gi[0][g][1] = MFMA16(a0, b1, gi[0][g][1]);
                gi[1][g][1] = MFMA16(a1, b1, gi[1][g][1]);
            }
        #pragma unroll
        for (int g = 0; g < 3; ++g)
            #pragma unroll
            for (int j = 0; j < 2; ++j) {
                float bias = ld1<F32>(bih, g * H + cc2[j]);
                if (g < 2) bias += ld1<F32>(bhh, g * H + cc2[j]);
                #pragma unroll
                for (int mt = 0; mt < 2; ++mt)
                    #pragma unroll
                    for (int r = 0; r < 4; ++r) gi[mt][g][j][r] += bias;
            }
    }
    // (no barrier needed: first conflicting zb0 write is at it=1 after barrier A(1))

    // ---- Pipelined loop: GRU step it | tail Wc(it-1) | tail Wmu(it-2) ----
    float hreg[2][2][4] = {};
    const unsigned short* haP0 = hb + m16 * LDP + q * 8;
    const unsigned short* haP1 = haP0 + 16 * LDP;
    const int mto = (cg >> 1) & 1;     // tail head tile (waves 8..11)
    const int nto = cg & 1;
    const float bmuv = ld1<F32>(bmu, nto * 16 + m16);
    const bool doMu = (!isG) && (cg < 4);

    #pragma unroll 1
    for (int it = 0; it < LSTEPS + 2; ++it) {
        float yv[2][2][4];
        float zv[2][2][4];
        f32x4 o = {};
        if (isG) {
            if (it < LSTEPS) {
                f32x4 gh[2][3][2] = {};
                if (it > 0) {
                    #pragma unroll
                    for (int g = 0; g < 3; ++g)
                        #pragma unroll
                        for (int kk = 0; kk < 8; ++kk) {
                            bf16x8 a0 = lds8(haP0 + kk * 32);
                            bf16x8 a1 = lds8(haP1 + kk * 32);
                            bf16x8 b0 = pk8(WHH_E + (size_t)(((cg * 3 + g) * 8 + kk) * 2 + 0) * 512 + lane8);
                            bf16x8 b1 = pk8(WHH_E + (size_t)(((cg * 3 + g) * 8 + kk) * 2 + 1) * 512 + lane8);
                            gh[0][g][0] = MFMA16(a0, b0, gh[0][g][0]);
                            gh[1][g][0] = MFMA16(a1, b0, gh[1][g][0]);
                            gh[0][g][1] = MFMA16(a0, b1, gh[0][g][1]);
                            gh[1][g][1] = MFMA16(a1, b1, gh[1][g][1]);
                        }
                }
                #pragma unroll
                for (int mt = 0; mt < 2; ++mt)
                    #pragma unroll
                    for (int j = 0; j < 2; ++j)
                        #pragma unroll
                        for (int r = 0; r < 4; ++r) {
                            float rr = sigm(gi[mt][0][j][r] + gh[mt][0][j][r]);
                            float zz = sigm(gi[mt][1][j][r] + gh[mt][1][j][r]);
                            float nin = gi[mt][2][j][r] + rr * (gh[mt][2][j][r] + bhhn[j]);
                            float nn = 2.0f * sigm(2.0f * nin) - 1.0f;   // tanh
                            float hh = (1.0f - zz) * nn + zz * hreg[mt][j][r];
                            hreg[mt][j][r] = hh;
                            float y = hh * s2v[j] + t2v[j];
                            yv[mt][j][r] = (y >= 0.0f) ? y : a2v * y;
                        }
            }
        } else {
            // tail: Wc on y(it-1)
            if (it >= 1 && it <= LSTEPS) {
                const unsigned short* ya0 = ybs[(it - 1) & 1] + m16 * LDP + q * 8;
                const unsigned short* ya1 = ya0 + 16 * LDP;
                f32x4 w2[2][2] = {};
                #pragma unroll
                for (int kk = 0; kk < 8; ++kk) {
                    bf16x8 a0 = lds8(ya0 + kk * 32);
                    bf16x8 a1 = lds8(ya1 + kk * 32);
                    bf16x8 b0 = pk8(WC_E + (size_t)((cg * 8 + kk) * 2 + 0) * 512 + lane8);
                    bf16x8 b1 = pk8(WC_E + (size_t)((cg * 8 + kk) * 2 + 1) * 512 + lane8);
                    w2[0][0] = MFMA16(a0, b0, w2[0][0]);
                    w2[1][0] = MFMA16(a1, b0, w2[1][0]);
                    w2[0][1] = MFMA16(a0, b1, w2[0][1]);
                    w2[1][1] = MFMA16(a1, b1, w2[1][1]);
                }
                #pragma unroll
                for (int mt = 0; mt < 2; ++mt)
                    #pragma unroll
                    for (int j = 0; j < 2; ++j)
                        #pragma unroll
                        for (int r = 0; r < 4; ++r) {
                            float z0 = w2[mt][j][r] * s3v[j] + t3f[j];
                            zv[mt][j][r] = (z0 >= 0.0f) ? z0 : a3v * z0;
                        }
            }
            // tail: Wmu on z(it-2) -> out
            if (doMu && it >= 2) {
                const unsigned short* za = zbs[it & 1] + (mto * 16 + m16) * LDP + q * 8;
                #pragma unroll
                for (int kk = 0; kk < 8; ++kk) {
                    bf16x8 a = lds8(za + kk * 32);
                    bf16x8 b = pk8(WMU_E + (size_t)(nto * 8 + kk) * 512 + lane8);
                    o = MFMA16(a, b, o);
                }
            }
        }
        __syncthreads();   // A: all reads of hb / yb[p] / zb[s] complete
        if (isG) {
            if (it < LSTEPS) {
                unsigned short* ybp = ybs[it & 1];
                #pragma unroll
                for (int mt = 0; mt < 2; ++mt)
                    #pragma unroll
                    for (int j = 0; j < 2; ++j)
                        #pragma unroll
                        for (int r = 0; r < 4; ++r) {
                            const int idx = (mt * 16 + q * 4 + r) * LDP + cc2[j];
                            hb[idx] = f2bs(hreg[mt][j][r]);
                            ybp[idx] = f2bs(yv[mt][j][r]);
                        }
            }
        } else {
            if (it >= 1 && it <= LSTEPS) {
                unsigned short* zbp = zbs[(it - 1) & 1];
                #pragma unroll
                for (int mt = 0; mt < 2; ++mt)
                    #pragma unroll
                    for (int j = 0; j < 2; ++j)
                        #pragma unroll
                        for (int r = 0; r < 4; ++r)
                            zbp[(mt * 16 + q * 4 + r) * LDP + cc2[j]] = f2bs(zv[mt][j][r]);
            }
            if (doMu && it >= 2) {
                const int to = it - 2;
                #pragma unroll
                for (int r = 0; r < 4; ++r) {
                    float vv = o[r] + bmuv;
                    const size_t oi = (size_t)(row0 + mto * 16 + q * 4 + r) * (LSTEPS * CO)
                                    + to * CO + nto * 16 + m16;
                    if constexpr (F32) ((float*)out)[oi] = vv;
                    else               ((__hip_bfloat16*)out)[oi] = __float2bfloat16(vv);
                }
            }
        }
        __syncthreads();   // B: writes visible
    }
}

__global__ __launch_bounds__(1024, 2) void comm_fast(
    const void* hw, const void* blin,
    const void* g1, const void* be1, const void* m1, const void* v1, const void* a1,
    const void* bih, const void* bhh,
    const void* g2, const void* be2, const void* m2, const void* v2, const void* a2,
    const void* bc,
    const void* g3, const void* be3, const void* m3, const void* v3, const void* a3,
    const void* bmu,
    void* out)
{
    __shared__ __align__(16) unsigned short hb[32 * LDP];
    __shared__ __align__(16) unsigned short yb0[32 * LDP];
    __shared__ __align__(16) unsigned short yb1[32 * LDP];
    __shared__ __align__(16) unsigned short zb0[32 * LDP];
    __shared__ __align__(16) unsigned short zb1[32 * LDP];
    if (g_flag) {
        fast_pipe<true >(hw, blin, g1, be1, m1, v1, a1, bih, bhh,
                         g2, be2, m2, v2, a2, bc, g3, be3, m3, v3, a3, bmu,
                         out, hb, yb0, yb1, zb0, zb1);
    } else {
        fast_pipe<false>(hw, blin, g1, be1, m1, v1, a1, bih, bhh,
                         g2, be2, m2, v2, a2, bc, g3, be3, m3, v3, a3, bmu,
                         out, hb, yb0, yb1, zb0, zb1);
    }
}

extern "C" void kernel_launch(void* const* d_in, const int* in_sizes, int n_in,
                              void* d_out, int out_size, void* d_ws, size_t ws_size,
                              hipStream_t stream) {
    (void)in_sizes; (void)n_in; (void)out_size; (void)d_ws; (void)ws_size;
    detect_dtype<<<dim3(1), dim3(1), 0, stream>>>(d_in[6]);
    prepack<<<dim3(308), dim3(256), 0, stream>>>(
        d_in[1], d_in[8], d_in[9], d_in[17], d_in[24]);
    comm_fast<<<dim3(256), dim3(1024), 0, stream>>>(
        d_in[0], d_in[2],
        d_in[3], d_in[4], d_in[5], d_in[6], d_in[7],
        d_in[10], d_in[11],
        d_in[12], d_in[13], d_in[14], d_in[15], d_in[16],
        d_in[18],
        d_in[19], d_in[20], d_in[21], d_in[22], d_in[23],
        d_in[25],
        d_out);
}

// Round 10
// 785.376 us; speedup vs baseline: 1.0708x; 1.0708x over previous
//
#include <hip/hip_runtime.h>
#include <hip/hip_bf16.h>

// Fused Comm_OUT pipeline, batch-row-parallel (GRU recurrence is per-row).
// Round-10: ONE barrier per GRU step. hb/yb/zb are parity double-buffered:
// iteration it reads parity p=it&1 (h(t-1), y(t-1), z(t-2)) and writes
// parity 1-p (h(t), y(t), z(t-1)) -> a single end-of-iteration
// __syncthreads() satisfies every dependency. The same 8 waves issue the
// Whh+Wc+Wmu load streams in one window (~66 wave-loads in flight vs r7's
// 3 barrier-drained chunks) -> latency overlap without wave specialization.
// 512 threads (8 waves), BM=32, 256 blocks (1/CU), __launch_bounds__(512,1)
// so the compiler has up to 256 VGPR (measured: 1024-thread blocks are
// force-capped at 64 VGPR -> spills; (512,2) gave 128; we need ~180).
// Packed bf16 weight streams (g_wpk) + 2 m-tiles per wave (r7's
// transaction-optimal layout, unchanged -> isolates the barrier term).
// Runtime dtype detection (inputs fp32 or bf16) via g_flag.

typedef __attribute__((ext_vector_type(8))) short bf16x8;   // 8 x bf16 (4 VGPRs)
typedef __attribute__((ext_vector_type(4))) float f32x4;    // MFMA accumulator

#define MFMA16(a, b, c) __builtin_amdgcn_mfma_f32_16x16x32_bf16((a), (b), (c), 0, 0, 0)

constexpr int F   = 640;
constexpr int H   = 256;
constexpr int LSTEPS = 20;
constexpr int CO  = 32;
constexpr int LDP = 264;   // padded bf16 row stride (16B-aligned rows)

// packed-weight element offsets inside g_wpk
constexpr size_t WHH_E  = 0;                    // 8cg*3g*8kk*2j*64lane*8 = 196608
constexpr size_t WIH_E  = 196608;               // 196608
constexpr size_t WC_E   = 393216;               // 8cg*8kk*2j*64*8       = 65536
constexpr size_t WMU_E  = 458752;               // 2nt*8kk*64*8          = 8192
constexpr size_t WLIN_E = 466944;               // 8cg*20kk*2j*64*8      = 163840
constexpr size_t PK_ELEMS = 630784;

__device__ __align__(16) unsigned short g_wpk[PK_ELEMS];
__device__ int g_flag;     // 1 = inputs are fp32

__device__ __forceinline__ float bf2f(__hip_bfloat16 x) { return __bfloat162float(x); }
__device__ __forceinline__ unsigned short f2bs(float f) {
    __hip_bfloat16 h = __float2bfloat16(f);
    return *reinterpret_cast<unsigned short*>(&h);
}
__device__ __forceinline__ bf16x8 lds8(const unsigned short* p) {
    return *reinterpret_cast<const bf16x8*>(p);
}
__device__ __forceinline__ bf16x8 pk8(size_t eoff) {
    return *reinterpret_cast<const bf16x8*>(g_wpk + eoff);
}
__device__ __forceinline__ float sigm(float x) {
    return 1.0f / (1.0f + __expf(-x));
}

template<bool F32>
__device__ __forceinline__ bf16x8 g8(const void* base, size_t off) {
    if constexpr (!F32) {
        return *reinterpret_cast<const bf16x8*>((const __hip_bfloat16*)base + off);
    } else {
        const float* f = (const float*)base + off;
        float4 lo = *reinterpret_cast<const float4*>(f);
        float4 hi = *reinterpret_cast<const float4*>(f + 4);
        bf16x8 r;
        r[0] = (short)f2bs(lo.x); r[1] = (short)f2bs(lo.y);
        r[2] = (short)f2bs(lo.z); r[3] = (short)f2bs(lo.w);
        r[4] = (short)f2bs(hi.x); r[5] = (short)f2bs(hi.y);
        r[6] = (short)f2bs(hi.z); r[7] = (short)f2bs(hi.w);
        return r;
    }
}

template<bool F32>
__device__ __forceinline__ float ld1(const void* base, int i) {
    if constexpr (!F32) return bf2f(((const __hip_bfloat16*)base)[i]);
    else                return ((const float*)base)[i];
}

// ---------------- dtype detect: v1 (uniform[0.5,1.5]) ----------------
__global__ void detect_dtype(const void* v1) {
    const unsigned short* u = (const unsigned short*)v1;
    int f32 = 0;
    for (int i = 0; i < 8; ++i) {
        unsigned short s = u[i];
        __hip_bfloat16 h = *reinterpret_cast<__hip_bfloat16*>(&s);
        float v = __bfloat162float(h);
        if (!(v >= 0.25f && v <= 2.0f)) f32 = 1;
    }
    g_flag = f32;
}

// ---------------- weight pre-pack (fp32|bf16 -> bf16 fragment streams) ----------------
__device__ __forceinline__ unsigned short cvt1(const void* p, size_t i, bool f32) {
    if (f32) return f2bs(((const float*)p)[i]);
    return ((const unsigned short*)p)[i];
}

__global__ void prepack(const void* Wlin, const void* Wih, const void* Whh,
                        const void* Wc, const void* Wmu) {
    const bool f32 = (g_flag != 0);
    const int gid = blockIdx.x * 256 + threadIdx.x;
    const void* src;
    size_t dbase;
    int row, col0, ncols;
    if (gid < 24576) {                       // Whh [768,256]
        int idx = gid;
        int lane = idx & 63, j = (idx >> 6) & 1, kk = (idx >> 7) & 7;
        int t2 = idx >> 10, g = t2 % 3, w = t2 / 3;
        row = g * 256 + w * 32 + j * 16 + (lane & 15);
        col0 = kk * 32 + (lane >> 4) * 8;
        ncols = 256; src = Whh; dbase = WHH_E + (size_t)idx * 8;
    } else if (gid < 49152) {                // Wih [768,256]
        int idx = gid - 24576;
        int lane = idx & 63, j = (idx >> 6) & 1, kk = (idx >> 7) & 7;
        int t2 = idx >> 10, g = t2 % 3, w = t2 / 3;
        row = g * 256 + w * 32 + j * 16 + (lane & 15);
        col0 = kk * 32 + (lane >> 4) * 8;
        ncols = 256; src = Wih; dbase = WIH_E + (size_t)idx * 8;
    } else if (gid < 57344) {                // Wc [256,256]
        int idx = gid - 49152;
        int lane = idx & 63, j = (idx >> 6) & 1, kk = (idx >> 7) & 7, w = idx >> 10;
        row = w * 32 + j * 16 + (lane & 15);
        col0 = kk * 32 + (lane >> 4) * 8;
        ncols = 256; src = Wc; dbase = WC_E + (size_t)idx * 8;
    } else if (gid < 58368) {                // Wmu [32,256]
        int idx = gid - 57344;
        int lane = idx & 63, kk = (idx >> 6) & 7, w = idx >> 9;
        row = w * 16 + (lane & 15);
        col0 = kk * 32 + (lane >> 4) * 8;
        ncols = 256; src = Wmu; dbase = WMU_E + (size_t)idx * 8;
    } else if (gid < 78848) {                // Wlin [256,640]
        int idx = gid - 58368;
        int lane = idx & 63, j = (idx >> 6) & 1;
        int t1 = idx >> 7, kk = t1 % 20, w = t1 / 20;
        row = w * 32 + j * 16 + (lane & 15);
        col0 = kk * 32 + (lane >> 4) * 8;
        ncols = 640; src = Wlin; dbase = WLIN_E + (size_t)idx * 8;
    } else {
        return;
    }
    const size_t s0 = (size_t)row * ncols + col0;
    #pragma unroll
    for (int i = 0; i < 8; ++i) g_wpk[dbase + i] = cvt1(src, s0 + i, f32);
}

// ---------------- FAST PATH: 8 waves, 1 barrier/step, parity buffers ----------------
template<bool F32>
__device__ __forceinline__ void fast_pipe(
    const void* hw, const void* blin,
    const void* g1, const void* be1, const void* m1, const void* v1, const void* a1,
    const void* bih, const void* bhh,
    const void* g2, const void* be2, const void* m2, const void* v2, const void* a2,
    const void* bc,
    const void* g3, const void* be3, const void* m3, const void* v3, const void* a3,
    const void* bmu,
    void* out,
    unsigned short* hb0, unsigned short* hb1,
    unsigned short* yb0, unsigned short* yb1,
    unsigned short* zb0, unsigned short* zb1)
{
    const int tid  = threadIdx.x;
    const int cg   = tid >> 6;        // wave = column group (32 cols), 0..7
    const int lane = tid & 63;
    const int m16  = lane & 15;
    const int q    = lane >> 4;
    const int row0 = blockIdx.x * 32;
    const int c0 = cg * 32 + m16;
    const int c1 = c0 + 16;
    const int cc2[2] = { c0, c1 };
    const size_t lane8 = (size_t)lane * 8;

    // persistent per-step params (folded)
    float s2v[2], t2v[2], s3v[2], t3f[2], bhhn[2];
    #pragma unroll
    for (int j = 0; j < 2; ++j) {
        const int cc = cc2[j];
        float s;
        s = ld1<F32>(g2, cc) * rsqrtf(ld1<F32>(v2, cc) + 1e-5f);
        s2v[j] = s; t2v[j] = ld1<F32>(be2, cc) - ld1<F32>(m2, cc) * s;
        s = ld1<F32>(g3, cc) * rsqrtf(ld1<F32>(v3, cc) + 1e-5f);
        s3v[j] = s;
        t3f[j] = (ld1<F32>(bc, cc) - ld1<F32>(m3, cc)) * s + ld1<F32>(be3, cc);
        bhhn[j] = ld1<F32>(bhh, 2 * H + cc);
    }
    const float a2v = ld1<F32>(a2, 0), a3v = ld1<F32>(a3, 0);

    // ---- Phase 1: x = prelu(bn1(rows @ Wlin^T + blin)) -> yb0 ----
    {
        f32x4 xacc[2][2] = {};   // [mt][j]
        #pragma unroll 5
        for (int kk = 0; kk < F / 32; ++kk) {
            bf16x8 a0 = g8<F32>(hw, (size_t)(row0 + m16) * F + kk * 32 + q * 8);
            bf16x8 a1 = g8<F32>(hw, (size_t)(row0 + 16 + m16) * F + kk * 32 + q * 8);
            bf16x8 b0 = pk8(WLIN_E + (size_t)((cg * 20 + kk) * 2 + 0) * 512 + lane8);
            bf16x8 b1 = pk8(WLIN_E + (size_t)((cg * 20 + kk) * 2 + 1) * 512 + lane8);
            xacc[0][0] = MFMA16(a0, b0, xacc[0][0]);
            xacc[1][0] = MFMA16(a1, b0, xacc[1][0]);
            xacc[0][1] = MFMA16(a0, b1, xacc[0][1]);
            xacc[1][1] = MFMA16(a1, b1, xacc[1][1]);
        }
        #pragma unroll
        for (int j = 0; j < 2; ++j) {
            const int cc = cc2[j];
            float s = ld1<F32>(g1, cc) * rsqrtf(ld1<F32>(v1, cc) + 1e-5f);
            float t = ld1<F32>(be1, cc) - ld1<F32>(m1, cc) * s;
            float bl = ld1<F32>(blin, cc);
            float av = ld1<F32>(a1, 0);
            #pragma unroll
            for (int mt = 0; mt < 2; ++mt)
                #pragma unroll
                for (int r = 0; r < 4; ++r) {
                    float vv = (xacc[mt][j][r] + bl) * s + t;
                    vv = (vv >= 0.0f) ? vv : av * vv;
                    yb0[(mt * 16 + q * 4 + r) * LDP + cc] = f2bs(vv);
                }
        }
    }
    __syncthreads();   // x visible in yb0

    // ---- Phase 2: gi = x @ Wih^T + (bih + bhh[r,z])  (registers) ----
    f32x4 gi[2][3][2] = {};   // [mt][g][j]
    {
        const unsigned short* xa0 = yb0 + m16 * LDP + q * 8;
        const unsigned short* xa1 = xa0 + 16 * LDP;
        #pragma unroll
        for (int g = 0; g < 3; ++g)
            #pragma unroll
            for (int kk = 0; kk < 8; ++kk) {
                bf16x8 a0 = lds8(xa0 + kk * 32);
                bf16x8 a1 = lds8(xa1 + kk * 32);
                bf16x8 b0 = pk8(WIH_E + (size_t)(((cg * 3 + g) * 8 + kk) * 2 + 0) * 512 + lane8);
                bf16x8 b1 = pk8(WIH_E + (size_t)(((cg * 3 + g) * 8 + kk) * 2 + 1) * 512 + lane8);
                gi[0][g][0] = MFMA16(a0, b0, gi[0][g][0]);
                gi[1][g][0] = MFMA16(a1, b0, gi[1][g][0]);
                gi[0][g][1] = MFMA16(a0, b1, gi[0][g][1]);
                gi[1][g][1] = MFMA16(a1, b1, gi[1][g][1]);
            }
        #pragma unroll
        for (int g = 0; g < 3; ++g)
            #pragma unroll
            for (int j = 0; j < 2; ++j) {
                float bias = ld1<F32>(bih, g * H + cc2[j]);
                if (g < 2) bias += ld1<F32>(bhh, g * H + cc2[j]);
                #pragma unroll
                for (int mt = 0; mt < 2; ++mt)
                    #pragma unroll
                    for (int r = 0; r < 4; ++r) gi[mt][g][j][r] += bias;
            }
    }
    // no barrier needed: iteration 0 writes only parity-1 buffers (hb1/yb1),
    // and the first write to yb0 (it=1) happens after it=0's end barrier.

    // ---- Single-barrier pipelined loop ----
    // it: reads hb[p],yb[p],zb[p] (p=it&1): gh(it), Wc->z(it-1), Wmu->out(it-2)
    //     writes hb[1-p]=h(it), yb[1-p]=y(it), zb[1-p]=z(it-1); ONE barrier.
    float hreg[2][2][4] = {};
    unsigned short* hbs[2] = { hb0, hb1 };
    unsigned short* ybs[2] = { yb0, yb1 };
    unsigned short* zbs[2] = { zb0, zb1 };
    const int mto = (cg >> 1) & 1;
    const int nto = cg & 1;
    const float bmuv = (cg < 4) ? ld1<F32>(bmu, nto * 16 + m16) : 0.0f;

    #pragma unroll 1
    for (int it = 0; it < LSTEPS + 2; ++it) {
        const int p = it & 1;

        // gh = h(it-1) @ Whh^T  (reads hb[p])
        f32x4 gh[2][3][2] = {};
        if (it >= 1 && it < LSTEPS) {
            const unsigned short* ha0 = hbs[p] + m16 * LDP + q * 8;
            const unsigned short* ha1 = ha0 + 16 * LDP;
            #pragma unroll
            for (int g = 0; g < 3; ++g)
                #pragma unroll
                for (int kk = 0; kk < 8; ++kk) {
                    bf16x8 a0 = lds8(ha0 + kk * 32);
                    bf16x8 a1 = lds8(ha1 + kk * 32);
                    bf16x8 b0 = pk8(WHH_E + (size_t)(((cg * 3 + g) * 8 + kk) * 2 + 0) * 512 + lane8);
                    bf16x8 b1 = pk8(WHH_E + (size_t)(((cg * 3 + g) * 8 + kk) * 2 + 1) * 512 + lane8);
                    gh[0][g][0] = MFMA16(a0, b0, gh[0][g][0]);
                    gh[1][g][0] = MFMA16(a1, b0, gh[1][g][0]);
                    gh[0][g][1] = MFMA16(a0, b1, gh[0][g][1]);
                    gh[1][g][1] = MFMA16(a1, b1, gh[1][g][1]);
                }
        }

        // w2 = y(it-1) @ Wc^T  (reads yb[p])
        f32x4 w2[2][2] = {};
        if (it >= 1 && it <= LSTEPS) {
            const unsigned short* ya0 = ybs[p] + m16 * LDP + q * 8;
            const unsigned short* ya1 = ya0 + 16 * LDP;
            #pragma unroll
            for (int kk = 0; kk < 8; ++kk) {
                bf16x8 a0 = lds8(ya0 + kk * 32);
                bf16x8 a1 = lds8(ya1 + kk * 32);
                bf16x8 b0 = pk8(WC_E + (size_t)((cg * 8 + kk) * 2 + 0) * 512 + lane8);
                bf16x8 b1 = pk8(WC_E + (size_t)((cg * 8 + kk) * 2 + 1) * 512 + lane8);
                w2[0][0] = MFMA16(a0, b0, w2[0][0]);
                w2[1][0] = MFMA16(a1, b0, w2[1][0]);
                w2[0][1] = MFMA16(a0, b1, w2[0][1]);
                w2[1][1] = MFMA16(a1, b1, w2[1][1]);
            }
        }

        // o = z(it-2) @ Wmu^T  (reads zb[p]; waves 0..3)
        f32x4 o = {};
        if (cg < 4 && it >= 2) {
            const unsigned short* za = zbs[p] + (mto * 16 + m16) * LDP + q * 8;
            #pragma unroll
            for (int kk = 0; kk < 8; ++kk) {
                bf16x8 a = lds8(za + kk * 32);
                bf16x8 b = pk8(WMU_E + (size_t)(nto * 8 + kk) * 512 + lane8);
                o = MFMA16(a, b, o);
            }
        }

        // gates + h update + y; write hb[1-p], yb[1-p]
        if (it < LSTEPS) {
            unsigned short* hbw = hbs[1 - p];
            unsigned short* ybw = ybs[1 - p];
            #pragma unroll
            for (int mt = 0; mt < 2; ++mt)
                #pragma unroll
                for (int j = 0; j < 2; ++j)
                    #pragma unroll
                    for (int r = 0; r < 4; ++r) {
                        float rr = sigm(gi[mt][0][j][r] + gh[mt][0][j][r]);
                        float zz = sigm(gi[mt][1][j][r] + gh[mt][1][j][r]);
                        float nin = gi[mt][2][j][r] + rr * (gh[mt][2][j][r] + bhhn[j]);
                        float nn = 2.0f * sigm(2.0f * nin) - 1.0f;   // tanh
                        float hh = (1.0f - zz) * nn + zz * hreg[mt][j][r];
                        hreg[mt][j][r] = hh;
                        float y = hh * s2v[j] + t2v[j];
                        y = (y >= 0.0f) ? y : a2v * y;
                        const int idx = (mt * 16 + q * 4 + r) * LDP + cc2[j];
                        hbw[idx] = f2bs(hh);
                        ybw[idx] = f2bs(y);
                    }
        }

        // z(it-1) = prelu(bn3(w2)); write zb[1-p]
        if (it >= 1 && it <= LSTEPS) {
            unsigned short* zbw = zbs[1 - p];
            #pragma unroll
            for (int mt = 0; mt < 2; ++mt)
                #pragma unroll
                for (int j = 0; j < 2; ++j)
                    #pragma unroll
                    for (int r = 0; r < 4; ++r) {
                        float z0 = w2[mt][j][r] * s3v[j] + t3f[j];
                        z0 = (z0 >= 0.0f) ? z0 : a3v * z0;
                        zbw[(mt * 16 + q * 4 + r) * LDP + cc2[j]] = f2bs(z0);
                    }
        }

        // out(it-2) = o + bmu
        if (cg < 4 && it >= 2) {
            const int to = it - 2;
            #pragma unroll
            for (int r = 0; r < 4; ++r) {
                float vv = o[r] + bmuv;
                const size_t oi = (size_t)(row0 + mto * 16 + q * 4 + r) * (LSTEPS * CO)
                                + to * CO + nto * 16 + m16;
                if constexpr (F32) ((float*)out)[oi] = vv;
                else               ((__hip_bfloat16*)out)[oi] = __float2bfloat16(vv);
            }
        }

        __syncthreads();   // the ONE barrier: all parity-p reads done, 1-p writes visible
    }
}

__global__ __launch_bounds__(512, 1) void comm_fast(
    const void* hw, const void* blin,
    const void* g1, const void* be1, const void* m1, const void* v1, const void* a1,
    const void* bih, const void* bhh,
    const void* g2, const void* be2, const void* m2, const void* v2, const void* a2,
    const void* bc,
    const void* g3, const void* be3, const void* m3, const void* v3, const void* a3,
    const void* bmu,
    void* out)
{
    __shared__ __align__(16) unsigned short hb0[32 * LDP];
    __shared__ __align__(16) unsigned short hb1[32 * LDP];
    __shared__ __align__(16) unsigned short yb0[32 * LDP];
    __shared__ __align__(16) unsigned short yb1[32 * LDP];
    __shared__ __align__(16) unsigned short zb0[32 * LDP];
    __shared__ __align__(16) unsigned short zb1[32 * LDP];
    if (g_flag) {
        fast_pipe<true >(hw, blin, g1, be1, m1, v1, a1, bih, bhh,
                         g2, be2, m2, v2, a2, bc, g3, be3, m3, v3, a3, bmu,
                         out, hb0, hb1, yb0, yb1, zb0, zb1);
    } else {
        fast_pipe<false>(hw, blin, g1, be1, m1, v1, a1, bih, bhh,
                         g2, be2, m2, v2, a2, bc, g3, be3, m3, v3, a3, bmu,
                         out, hb0, hb1, yb0, yb1, zb0, zb1);
    }
}

extern "C" void kernel_launch(void* const* d_in, const int* in_sizes, int n_in,
                              void* d_out, int out_size, void* d_ws, size_t ws_size,
                              hipStream_t stream) {
    (void)in_sizes; (void)n_in; (void)out_size; (void)d_ws; (void)ws_size;
    detect_dtype<<<dim3(1), dim3(1), 0, stream>>>(d_in[6]);
    prepack<<<dim3(308), dim3(256), 0, stream>>>(
        d_in[1], d_in[8], d_in[9], d_in[17], d_in[24]);
    comm_fast<<<dim3(256), dim3(512), 0, stream>>>(
        d_in[0], d_in[2],
        d_in[3], d_in[4], d_in[5], d_in[6], d_in[7],
        d_in[10], d_in[11],
        d_in[12], d_in[13], d_in[14], d_in[15], d_in[16],
        d_in[18],
        d_in[19], d_in[20], d_in[21], d_in[22], d_in[23],
        d_in[25],
        d_out);
}